// Round 2
// baseline (1319.178 us; speedup 1.0000x reference)
//
#include <hip/hip_runtime.h>
#include <hip/hip_bf16.h>

// DeepSeek-V2 MLA prefill on gfx950. B=2,S=2048,HID=2048,NH=16,HD=128,QLR=1536,KVLR=512.
// R2: same structure as R1, workspace cut 293MB -> 144.2MB via static overlays
// (R1 crash diagnosed as ws overflow / GPU page fault).

using bf16 = __hip_bfloat16;
typedef __attribute__((ext_vector_type(8))) short short8;   // 8 bf16 = 4 VGPR
typedef __attribute__((ext_vector_type(4))) float f32x4;

__device__ __forceinline__ float b2f(bf16 x) { return __bfloat162float(x); }
__device__ __forceinline__ bf16 f2b(float x) { return __float2bfloat16(x); }

// ---------------------------------------------------------------------------
// Generic tiled MFMA GEMM: C[m,n] = sum_k A[m,k]*B[n,k]
// A: M x K bf16 (lda), B: N x K bf16 (ldb), C: M x N (ldc), f32 or bf16 out.
// Batch: z -> z0=z/zdiv, z1=z%zdiv; element-offsets base += z0*s?0 + z1*s?1.
// Tiles: 128x128x32, 256 threads = 4 waves in 2x2, each wave 4x4 MFMA 16x16x32.
// Requires: M%128==0, N%128==0, K%32==0, lda/ldb multiples of 8 (16B loads).
// ---------------------------------------------------------------------------
template<bool OUT_BF16>
__global__ __launch_bounds__(256) void gemm_bt(
    const bf16* __restrict__ A, const bf16* __restrict__ B, void* __restrict__ Cv,
    int M, int N, int K, int lda, int ldb, int ldc,
    long sa0, long sa1, long sb0, long sb1, long sc0, long sc1, int zdiv)
{
  constexpr int LP = 40;                 // 32 + 8 pad (80B rows: 16B-aligned, <=2-way bank alias)
  __shared__ bf16 As[128 * LP];
  __shared__ bf16 Bs[128 * LP];

  const int z = blockIdx.z, z0 = z / zdiv, z1 = z % zdiv;
  A += z0 * sa0 + z1 * sa1;
  B += z0 * sb0 + z1 * sb1;
  const long coff = z0 * sc0 + z1 * sc1;

  const int m0 = blockIdx.x * 128, n0 = blockIdx.y * 128;
  const int tid = threadIdx.x, lane = tid & 63, wave = tid >> 6;
  const int wm = (wave & 1) * 64, wn = (wave >> 1) * 64;   // 2x2 wave grid, 64x64 each
  const int mrow = lane & 15, quad = lane >> 4;
  const int srow = tid >> 2, scol = (tid & 3) * 8;          // staging: 4 threads per 32-col row

  f32x4 acc[4][4];
  #pragma unroll
  for (int i = 0; i < 4; i++)
    #pragma unroll
    for (int j = 0; j < 4; j++)
      #pragma unroll
      for (int r = 0; r < 4; r++) acc[i][j][r] = 0.0f;

  const bf16* ag = A + (long)(m0 + srow) * lda + scol;
  const bf16* bg = B + (long)(n0 + srow) * ldb + scol;

  for (int k0 = 0; k0 < K; k0 += 32) {
    short8 a0 = *(const short8*)(ag + k0);
    short8 a1 = *(const short8*)(ag + k0 + 64l * lda);
    short8 b0 = *(const short8*)(bg + k0);
    short8 b1 = *(const short8*)(bg + k0 + 64l * ldb);
    __syncthreads();                                   // previous iter's frag reads done
    *(short8*)&As[srow * LP + scol] = a0;
    *(short8*)&As[(srow + 64) * LP + scol] = a1;
    *(short8*)&Bs[srow * LP + scol] = b0;
    *(short8*)&Bs[(srow + 64) * LP + scol] = b1;
    __syncthreads();

    short8 af[4], bfr[4];
    #pragma unroll
    for (int i = 0; i < 4; i++) {
      // A-frag: A[m=lane&15][k=quad*8+j]; B-frag mirrors with n=lane&15 (B^T rows)
      af[i]  = *(const short8*)&As[(wm + i * 16 + mrow) * LP + quad * 8];
      bfr[i] = *(const short8*)&Bs[(wn + i * 16 + mrow) * LP + quad * 8];
    }
    #pragma unroll
    for (int i = 0; i < 4; i++)
      #pragma unroll
      for (int j = 0; j < 4; j++)
        acc[i][j] = __builtin_amdgcn_mfma_f32_16x16x32_bf16(af[i], bfr[j], acc[i][j], 0, 0, 0);
  }

  // C/D layout (m89/m91-verified): col = lane&15, row = quad*4 + reg
  const int cm = m0 + wm + quad * 4;
  const int cn = n0 + wn + mrow;
  if (OUT_BF16) {
    bf16* C = (bf16*)Cv + coff;
    #pragma unroll
    for (int i = 0; i < 4; i++)
      #pragma unroll
      for (int j = 0; j < 4; j++)
        #pragma unroll
        for (int r = 0; r < 4; r++)
          C[(long)(cm + i * 16 + r) * ldc + cn + j * 16] = f2b(acc[i][j][r]);
  } else {
    float* C = (float*)Cv + coff;
    #pragma unroll
    for (int i = 0; i < 4; i++)
      #pragma unroll
      for (int j = 0; j < 4; j++)
        #pragma unroll
        for (int r = 0; r < 4; r++)
          C[(long)(cm + i * 16 + r) * ldc + cn + j * 16] = acc[i][j][r];
  }
}

// --------------------------- aux kernels -----------------------------------

__global__ __launch_bounds__(256) void cvt_kernel(const float* __restrict__ in,
                                                  bf16* __restrict__ out, long n)
{
  long i = (long)blockIdx.x * 256 + threadIdx.x;
  if (i < n) out[i] = f2b(in[i]);
}

// oabsT[h][d][c] = kv_b_W[c,h,1,d]   (bf16, K(c)-contiguous rows for gemm_bt)
__global__ __launch_bounds__(256) void oabsT_kernel(const float* __restrict__ kvb,
                                                    bf16* __restrict__ oT)
{
  long idx = (long)blockIdx.x * 256 + threadIdx.x;   // 16*128*512
  int c = (int)(idx & 511);
  long r = idx >> 9;                                 // h*128 + d
  int d = (int)(r & 127);
  int h = (int)(r >> 7);
  oT[idx] = f2b(kvb[(long)c * 4096 + h * 256 + 128 + d]);
}

// q_a_n = (q_a + bias) * rsqrt(sum(x^2) + eps) * w      (ref uses SUM not mean)
__global__ __launch_bounds__(256) void rmsnorm_kernel(const float* __restrict__ qa,
                                                      const float* __restrict__ bias,
                                                      const float* __restrict__ w,
                                                      bf16* __restrict__ out)
{
  const int s = blockIdx.x;                          // 4096 rows of 1536
  const int tid = threadIdx.x, lane = tid & 63, wave = tid >> 6;
  const float* row = qa + (long)s * 1536;
  float v[6]; float ss = 0.f;
  #pragma unroll
  for (int i = 0; i < 6; i++) {
    int t = tid + i * 256;
    v[i] = row[t] + bias[t];
    ss += v[i] * v[i];
  }
  #pragma unroll
  for (int off = 32; off; off >>= 1) ss += __shfl_xor(ss, off);
  __shared__ float red[4];
  if (lane == 0) red[wave] = ss;
  __syncthreads();
  ss = red[0] + red[1] + red[2] + red[3];
  float rs = rsqrtf(ss + 1e-6f);
  bf16* orow = out + (long)s * 1536;
  #pragma unroll
  for (int i = 0; i < 6; i++) {
    int t = tid + i * 256;
    orow[t] = f2b(v[i] * rs * w[t]);
  }
}

// RoPE on q_pe: read q[b,s,h,128+d], write rotated into Q640[b,h,s,512+d]
__global__ __launch_bounds__(256) void rope_q_kernel(const bf16* __restrict__ q,
                                                     bf16* __restrict__ Q640)
{
  long idx = (long)blockIdx.x * 256 + threadIdx.x;   // B*NH*S*64
  int d = (int)(idx & 63);
  long r = idx >> 6;                                 // (b*16+h)*2048 + s
  int s = (int)(r & 2047);
  long bh = r >> 11;
  int h = (int)(bh & 15);
  long b = bh >> 4;
  const bf16* qrow = q + (b * 2048 + s) * 4096l + h * 256 + 128;
  float x1 = b2f(qrow[d]), x2 = b2f(qrow[d + 64]);
  float ang = (float)s * powf(10000.0f, -(float)d * (1.0f / 64.0f));
  float sn, cs; sincosf(ang, &sn, &cs);
  bf16* orow = Q640 + (bh * 2048 + s) * 640 + 512;
  orow[d]      = f2b(x1 * cs - x2 * sn);
  orow[d + 64] = f2b(x2 * cs + x1 * sn);
}

// RoPE on k_pe: in place on ckv_full[...,512:640]
__global__ __launch_bounds__(256) void rope_k_kernel(bf16* __restrict__ ckv)
{
  long idx = (long)blockIdx.x * 256 + threadIdx.x;   // B*S*64
  int d = (int)(idx & 63);
  long r = idx >> 6;                                 // b*2048 + t
  int t = (int)(r & 2047);
  bf16* row = ckv + r * 640 + 512;
  float x1 = b2f(row[d]), x2 = b2f(row[d + 64]);
  float ang = (float)t * powf(10000.0f, -(float)d * (1.0f / 64.0f));
  float sn, cs; sincosf(ang, &sn, &cs);
  row[d]      = f2b(x1 * cs - x2 * sn);
  row[d + 64] = f2b(x2 * cs + x1 * sn);
}

// ckvT[b][c][t] = ckv_full[b][t][c], c<512  (K(t)-contiguous rows for PV gemm)
__global__ __launch_bounds__(256) void ckvT_kernel(const bf16* __restrict__ ckv,
                                                   bf16* __restrict__ ckvT)
{
  long idx = (long)blockIdx.x * 256 + threadIdx.x;   // B*512*2048
  int t = (int)(idx & 2047);
  long r = idx >> 11;                                // b*512 + c
  int c = (int)(r & 511);
  long b = r >> 9;
  ckvT[idx] = ckv[(b * 2048 + t) * 640 + c];
}

// rowwise softmax over 2048, in-place on bf16 scores: p = softmax(s*scale + mask)
__global__ __launch_bounds__(256) void softmax_kernel(bf16* __restrict__ S,
                                                      const float* __restrict__ mask,
                                                      float scale)
{
  const int s = blockIdx.x;                          // 0..2047
  const int pair = blockIdx.y;                       // local pair in chunk
  bf16* row = S + ((long)pair * 2048 + s) * 2048;
  const float* mrow = mask + (long)s * 2048;         // mask pre-offset by b*S*S
  const int tid = threadIdx.x, lane = tid & 63, wave = tid >> 6;
  float v[8]; float mx = -3.4e38f;
  #pragma unroll
  for (int i = 0; i < 8; i++) {
    int t = tid + i * 256;
    v[i] = b2f(row[t]) * scale + mrow[t];
    mx = fmaxf(mx, v[i]);
  }
  #pragma unroll
  for (int off = 32; off; off >>= 1) mx = fmaxf(mx, __shfl_xor(mx, off));
  __shared__ float red[4];
  if (lane == 0) red[wave] = mx;
  __syncthreads();
  mx = fmaxf(fmaxf(red[0], red[1]), fmaxf(red[2], red[3]));
  float ss = 0.f;
  #pragma unroll
  for (int i = 0; i < 8; i++) { v[i] = __expf(v[i] - mx); ss += v[i]; }
  #pragma unroll
  for (int off = 32; off; off >>= 1) ss += __shfl_xor(ss, off);
  __syncthreads();                                   // red reuse
  if (lane == 0) red[wave] = ss;
  __syncthreads();
  ss = red[0] + red[1] + red[2] + red[3];
  float inv = 1.0f / ss;
  #pragma unroll
  for (int i = 0; i < 8; i++) {
    int t = tid + i * 256;
    row[t] = f2b(v[i] * inv);
  }
}

// ---------------------------------------------------------------------------

extern "C" void kernel_launch(void* const* d_in, const int* in_sizes, int n_in,
                              void* d_out, int out_size, void* d_ws, size_t ws_size,
                              hipStream_t stream)
{
  const float* hidden = (const float*)d_in[0];   // (2,2048,2048)
  const float* mask   = (const float*)d_in[1];   // (2,1,2048,2048)
  const float* qaW    = (const float*)d_in[2];   // (1536,2048)
  const float* qab    = (const float*)d_in[3];   // (1536,)
  const float* qanw   = (const float*)d_in[4];   // (1536,)
  const float* qbW    = (const float*)d_in[5];   // (4096,1536)
  const float* kvaW   = (const float*)d_in[6];   // (640,2048)
  const float* kvbW   = (const float*)d_in[7];   // (512,16,2,128)
  const float* oW     = (const float*)d_in[8];   // (2048,2048)
  float* out = (float*)d_out;                    // (2,2048,2048) f32
  (void)in_sizes; (void)n_in; (void)out_size;

  // ---- static workspace layout, total 144,179,200 B (R1's 293MB crashed: ws overflow) ----
  char* ws = (char*)d_ws;
  if (ws_size < 144179200u) return;   // diagnostic: absmax-fail (not crash) => ws too small

  // P0 [0, 83,886,080): Q640 (2,16,2048,640) bf16. Written from S6 (rope_q) onward.
  // Overlays inside P0 (ALL dead before S6):
  bf16* Q640    = (bf16*)(ws + 0);
  float* qa_f   = (float*)(ws + 0);           // (4096,1536) f32, S2-S3, 25,165,824 B
  bf16* hiddenB = (bf16*)(ws + 25165824);     // 8,388,608 bf16, S1-S5, ends 41,943,040
  bf16* qan     = (bf16*)(ws + 41943040);     // (4096,1536), S3-S4, ends 54,525,952
  bf16* qaWB    = (bf16*)(ws + 54525952);     // (1536,2048), S1-S2, ends 60,817,408
  bf16* qbWB    = (bf16*)(ws + 60817408);     // (4096,1536), S1-S4, ends 73,400,320 <= 83,886,080
  // P1 [83,886,080, 117,440,512): time-shared qB (S4-S7) / Sbuf (S8) / attn_out (S9-S10)
  bf16* qB       = (bf16*)(ws + 83886080);    // (4096,4096) = (b,s,h,256)
  bf16* Sbuf     = (bf16*)(ws + 83886080);    // (4,2048,2048) score chunk
  bf16* attn_out = (bf16*)(ws + 83886080);    // (4096, 16*128)
  bf16* ckv     = (bf16*)(ws + 117440512);    // (2,2048,640), 5,242,880 B
  bf16* ckvT    = (bf16*)(ws + 122683392);    // (2,512,2048), 4,194,304 B
  bf16* kvaWB   = (bf16*)(ws + 126877696);    // (640,2048),   2,621,440 B
  bf16* kvbWB   = (bf16*)(ws + 129499136);    // (512,16,2,128), 4,194,304 B
  bf16* oWB     = (bf16*)(ws + 133693440);    // (2048,2048),  8,388,608 B
  bf16* oabsT   = (bf16*)(ws + 142082048);    // (16,128,512), 2,097,152 B -> end 144,179,200
  // outlat (b,h,s,512) has NO buffer: PV writes it into Q640's cols [0:512] (ldc=640)
  // of the chunk whose q_lat the scores-GEMM just consumed (stream-serialized, disjoint).

  // ---- S1: converts ----
  cvt_kernel<<<dim3(32768), 256, 0, stream>>>(hidden, hiddenB, 8388608l);
  cvt_kernel<<<dim3(12288), 256, 0, stream>>>(qaW, qaWB, 3145728l);
  cvt_kernel<<<dim3(24576), 256, 0, stream>>>(qbW, qbWB, 6291456l);
  cvt_kernel<<<dim3(5120),  256, 0, stream>>>(kvaW, kvaWB, 1310720l);
  cvt_kernel<<<dim3(8192),  256, 0, stream>>>(kvbW, kvbWB, 2097152l);
  cvt_kernel<<<dim3(16384), 256, 0, stream>>>(oW, oWB, 4194304l);
  oabsT_kernel<<<dim3(4096), 256, 0, stream>>>(kvbW, oabsT);

  // ---- S2: q_a = hidden @ qaW^T (f32) ; S3: rmsnorm -> qan bf16 ----
  gemm_bt<false><<<dim3(32, 12, 1), 256, 0, stream>>>(hiddenB, qaWB, qa_f,
      4096, 1536, 2048, 2048, 2048, 1536, 0, 0, 0, 0, 0, 0, 1);
  rmsnorm_kernel<<<dim3(4096), 256, 0, stream>>>(qa_f, qab, qanw, qan);

  // ---- S4: q = qan @ qbW^T -> qB (b,s,h,256) bf16 ----
  gemm_bt<true><<<dim3(32, 32, 1), 256, 0, stream>>>(qan, qbWB, qB,
      4096, 4096, 1536, 1536, 1536, 4096, 0, 0, 0, 0, 0, 0, 1);

  // ---- S5: ckv_full = hidden @ kvaW^T -> (b,t,640) bf16 ----
  gemm_bt<true><<<dim3(32, 5, 1), 256, 0, stream>>>(hiddenB, kvaWB, ckv,
      4096, 640, 2048, 2048, 2048, 640, 0, 0, 0, 0, 0, 0, 1);

  // ---- S6: RoPE + transpose ----
  rope_k_kernel<<<dim3(1024), 256, 0, stream>>>(ckv);
  rope_q_kernel<<<dim3(16384), 256, 0, stream>>>(qB, Q640);
  ckvT_kernel<<<dim3(8192), 256, 0, stream>>>(ckv, ckvT);

  // ---- S7: q_lat = q_nope @ q_absorb^T -> Q640[...,0:512], z=(h,b) ----
  gemm_bt<true><<<dim3(16, 4, 32), 256, 0, stream>>>(qB, kvbWB, Q640,
      2048, 512, 128, 4096, 4096, 640,
      256l, 8388608l, 256l, 0l, 1310720l, 20971520l, 2);

  // ---- S8: scores GEMM -> softmax -> PV GEMM, chunks of 4 (b,h)-pairs ----
  const float scale = 1.0f / sqrtf(640.0f);
  for (int c = 0; c < 8; ++c) {
    int b = c / 4;
    bf16* Qchunk = Q640 + (long)c * 4 * 1310720;   // 4 pairs x (2048x640)
    gemm_bt<true><<<dim3(16, 16, 4), 256, 0, stream>>>(Qchunk, ckv + (long)b * 1310720, Sbuf,
        2048, 2048, 640, 640, 640, 2048,
        1310720l, 0l, 0l, 0l, 4194304l, 0l, 1);
    softmax_kernel<<<dim3(2048, 4), 256, 0, stream>>>(Sbuf, mask + (long)b * 4194304, scale);
    // PV: out_lat -> back into Q640 cols [0:512] of this (consumed) chunk, ldc=640
    gemm_bt<true><<<dim3(16, 4, 4), 256, 0, stream>>>(Sbuf, ckvT + (long)b * 1048576, Qchunk,
        2048, 512, 2048, 2048, 2048, 640,
        4194304l, 0l, 0l, 0l, 1310720l, 0l, 1);
  }

  // ---- S9: attn_out[b,s,h*128+d] = sum_c outlat[(b,h),s,c]*oabsT[h,d,c], z=(h,b) ----
  gemm_bt<true><<<dim3(16, 1, 32), 256, 0, stream>>>(Q640, oabsT, attn_out,
      2048, 128, 512, 640, 512, 2048,
      1310720l, 20971520l, 65536l, 0l, 128l, 4194304l, 2);

  // ---- S10: out = attn_out @ oW^T (f32, final) ----
  gemm_bt<false><<<dim3(32, 16, 1), 256, 0, stream>>>(attn_out, oWB, out,
      4096, 2048, 2048, 2048, 2048, 2048, 0, 0, 0, 0, 0, 0, 1);
}

// Round 3
// 1305.075 us; speedup vs baseline: 1.0108x; 1.0108x over previous
//
#include <hip/hip_runtime.h>
#include <hip/hip_bf16.h>

// DeepSeek-V2 MLA prefill on gfx950. B=2,S=2048,HID=2048,NH=16,HD=128,QLR=1536,KVLR=512.
// R3: gemm_bt staging switched to async global_load_lds width=16 (m97 ladder step),
// unpadded LDS tile (lane-contiguous layout required by the DMA's lds addressing).

using bf16 = __hip_bfloat16;
typedef __attribute__((ext_vector_type(8))) short short8;   // 8 bf16 = 4 VGPR
typedef __attribute__((ext_vector_type(4))) float f32x4;

__device__ __forceinline__ float b2f(bf16 x) { return __bfloat162float(x); }
__device__ __forceinline__ bf16 f2b(float x) { return __float2bfloat16(x); }

typedef __attribute__((address_space(3))) unsigned lds_u32;
typedef const __attribute__((address_space(1))) unsigned glb_u32;
__device__ __forceinline__ void dma16(const bf16* g, bf16* l) {
  // async global->LDS, 16B/lane; LDS dst = wave-uniform base + lane*16 (m104/m108)
  __builtin_amdgcn_global_load_lds((glb_u32*)g, (lds_u32*)l, 16, 0, 0);
}

// ---------------------------------------------------------------------------
// Generic tiled MFMA GEMM: C[m,n] = sum_k A[m,k]*B[n,k]
// A: M x K bf16 (lda), B: N x K bf16 (ldb), C: M x N (ldc), f32 or bf16 out.
// Batch: z -> z0=z/zdiv, z1=z%zdiv; element-offsets base += z0*s?0 + z1*s?1.
// Tiles: 128x128x32, 256 threads = 4 waves in 2x2, each wave 4x4 MFMA 16x16x32.
// Requires: M%128==0, N%128==0, K%32==0, lda/ldb mult of 8, base ptrs 16B-aligned.
// ---------------------------------------------------------------------------
template<bool OUT_BF16>
__global__ __launch_bounds__(256) void gemm_bt(
    const bf16* __restrict__ A, const bf16* __restrict__ B, void* __restrict__ Cv,
    int M, int N, int K, int lda, int ldb, int ldc,
    long sa0, long sa1, long sb0, long sb1, long sc0, long sc1, int zdiv)
{
  // UNPADDED 128x32: staging LDS byte-offset == tid*16, as global_load_lds needs.
  // frag ds_read_b128 at row-stride 64B touches all 32 banks uniformly (8 words/bank
  // = the 1024B/instr floor), so no pad needed for conflicts.
  __shared__ bf16 As[128 * 32];
  __shared__ bf16 Bs[128 * 32];

  const int z = blockIdx.z, z0 = z / zdiv, z1 = z % zdiv;
  A += z0 * sa0 + z1 * sa1;
  B += z0 * sb0 + z1 * sb1;
  const long coff = z0 * sc0 + z1 * sc1;

  const int m0 = blockIdx.x * 128, n0 = blockIdx.y * 128;
  const int tid = threadIdx.x, lane = tid & 63, wave = tid >> 6;
  const int wm = (wave & 1) * 64, wn = (wave >> 1) * 64;   // 2x2 wave grid, 64x64 each
  const int mrow = lane & 15, quad = lane >> 4;
  const int srow = tid >> 2, scol = (tid & 3) * 8;          // 4 lanes cover one 32-col row

  f32x4 acc[4][4];
  #pragma unroll
  for (int i = 0; i < 4; i++)
    #pragma unroll
    for (int j = 0; j < 4; j++)
      #pragma unroll
      for (int r = 0; r < 4; r++) acc[i][j][r] = 0.0f;

  const bf16* ag = A + (long)(m0 + srow) * lda + scol;
  const bf16* bg = B + (long)(n0 + srow) * ldb + scol;
  // wave-uniform LDS bases; HW adds lane*16B. Wave w stages rows 16w..16w+15.
  bf16* as0 = As + wave * 512;            // rows 0..63  : bytes [0,4096)
  bf16* as1 = As + 2048 + wave * 512;     // rows 64..127: bytes [4096,8192)
  bf16* bs0 = Bs + wave * 512;
  bf16* bs1 = Bs + 2048 + wave * 512;

  for (int k0 = 0; k0 < K; k0 += 32) {
    __syncthreads();                       // prev iter's frag reads done
    dma16(ag + k0,             as0);
    dma16(ag + k0 + 64l * lda, as1);
    dma16(bg + k0,             bs0);
    dma16(bg + k0 + 64l * ldb, bs1);
    __syncthreads();                       // drains vmcnt(0) -> LDS tile visible

    short8 af[4], bfr[4];
    #pragma unroll
    for (int i = 0; i < 4; i++) {
      // A-frag: A[m=lane&15][k=quad*8+j]; B-frag mirrors with n=lane&15 (B^T rows)
      af[i]  = *(const short8*)&As[(wm + i * 16 + mrow) * 32 + quad * 8];
      bfr[i] = *(const short8*)&Bs[(wn + i * 16 + mrow) * 32 + quad * 8];
    }
    #pragma unroll
    for (int i = 0; i < 4; i++)
      #pragma unroll
      for (int j = 0; j < 4; j++)
        acc[i][j] = __builtin_amdgcn_mfma_f32_16x16x32_bf16(af[i], bfr[j], acc[i][j], 0, 0, 0);
  }

  // C/D layout (m89/m91-verified): col = lane&15, row = quad*4 + reg
  const int cm = m0 + wm + quad * 4;
  const int cn = n0 + wn + mrow;
  if (OUT_BF16) {
    bf16* C = (bf16*)Cv + coff;
    #pragma unroll
    for (int i = 0; i < 4; i++)
      #pragma unroll
      for (int j = 0; j < 4; j++)
        #pragma unroll
        for (int r = 0; r < 4; r++)
          C[(long)(cm + i * 16 + r) * ldc + cn + j * 16] = f2b(acc[i][j][r]);
  } else {
    float* C = (float*)Cv + coff;
    #pragma unroll
    for (int i = 0; i < 4; i++)
      #pragma unroll
      for (int j = 0; j < 4; j++)
        #pragma unroll
        for (int r = 0; r < 4; r++)
          C[(long)(cm + i * 16 + r) * ldc + cn + j * 16] = acc[i][j][r];
  }
}

// --------------------------- aux kernels -----------------------------------

__global__ __launch_bounds__(256) void cvt_kernel(const float* __restrict__ in,
                                                  bf16* __restrict__ out, long n)
{
  long i = (long)blockIdx.x * 256 + threadIdx.x;
  if (i < n) out[i] = f2b(in[i]);
}

// oabsT[h][d][c] = kv_b_W[c,h,1,d]   (bf16, K(c)-contiguous rows for gemm_bt)
__global__ __launch_bounds__(256) void oabsT_kernel(const float* __restrict__ kvb,
                                                    bf16* __restrict__ oT)
{
  long idx = (long)blockIdx.x * 256 + threadIdx.x;   // 16*128*512
  int c = (int)(idx & 511);
  long r = idx >> 9;                                 // h*128 + d
  int d = (int)(r & 127);
  int h = (int)(r >> 7);
  oT[idx] = f2b(kvb[(long)c * 4096 + h * 256 + 128 + d]);
}

// q_a_n = (q_a + bias) * rsqrt(sum(x^2) + eps) * w      (ref uses SUM not mean)
__global__ __launch_bounds__(256) void rmsnorm_kernel(const float* __restrict__ qa,
                                                      const float* __restrict__ bias,
                                                      const float* __restrict__ w,
                                                      bf16* __restrict__ out)
{
  const int s = blockIdx.x;                          // 4096 rows of 1536
  const int tid = threadIdx.x, lane = tid & 63, wave = tid >> 6;
  const float* row = qa + (long)s * 1536;
  float v[6]; float ss = 0.f;
  #pragma unroll
  for (int i = 0; i < 6; i++) {
    int t = tid + i * 256;
    v[i] = row[t] + bias[t];
    ss += v[i] * v[i];
  }
  #pragma unroll
  for (int off = 32; off; off >>= 1) ss += __shfl_xor(ss, off);
  __shared__ float red[4];
  if (lane == 0) red[wave] = ss;
  __syncthreads();
  ss = red[0] + red[1] + red[2] + red[3];
  float rs = rsqrtf(ss + 1e-6f);
  bf16* orow = out + (long)s * 1536;
  #pragma unroll
  for (int i = 0; i < 6; i++) {
    int t = tid + i * 256;
    orow[t] = f2b(v[i] * rs * w[t]);
  }
}

// RoPE on q_pe: read q[b,s,h,128+d], write rotated into Q640[b,h,s,512+d]
__global__ __launch_bounds__(256) void rope_q_kernel(const bf16* __restrict__ q,
                                                     bf16* __restrict__ Q640)
{
  long idx = (long)blockIdx.x * 256 + threadIdx.x;   // B*NH*S*64
  int d = (int)(idx & 63);
  long r = idx >> 6;                                 // (b*16+h)*2048 + s
  int s = (int)(r & 2047);
  long bh = r >> 11;
  int h = (int)(bh & 15);
  long b = bh >> 4;
  const bf16* qrow = q + (b * 2048 + s) * 4096l + h * 256 + 128;
  float x1 = b2f(qrow[d]), x2 = b2f(qrow[d + 64]);
  float ang = (float)s * powf(10000.0f, -(float)d * (1.0f / 64.0f));
  float sn, cs; sincosf(ang, &sn, &cs);
  bf16* orow = Q640 + (bh * 2048 + s) * 640 + 512;
  orow[d]      = f2b(x1 * cs - x2 * sn);
  orow[d + 64] = f2b(x2 * cs + x1 * sn);
}

// RoPE on k_pe: in place on ckv_full[...,512:640]
__global__ __launch_bounds__(256) void rope_k_kernel(bf16* __restrict__ ckv)
{
  long idx = (long)blockIdx.x * 256 + threadIdx.x;   // B*S*64
  int d = (int)(idx & 63);
  long r = idx >> 6;                                 // b*2048 + t
  int t = (int)(r & 2047);
  bf16* row = ckv + r * 640 + 512;
  float x1 = b2f(row[d]), x2 = b2f(row[d + 64]);
  float ang = (float)t * powf(10000.0f, -(float)d * (1.0f / 64.0f));
  float sn, cs; sincosf(ang, &sn, &cs);
  row[d]      = f2b(x1 * cs - x2 * sn);
  row[d + 64] = f2b(x2 * cs + x1 * sn);
}

// ckvT[b][c][t] = ckv_full[b][t][c], c<512  (K(t)-contiguous rows for PV gemm)
__global__ __launch_bounds__(256) void ckvT_kernel(const bf16* __restrict__ ckv,
                                                   bf16* __restrict__ ckvT)
{
  long idx = (long)blockIdx.x * 256 + threadIdx.x;   // B*512*2048
  int t = (int)(idx & 2047);
  long r = idx >> 11;                                // b*512 + c
  int c = (int)(r & 511);
  long b = r >> 9;
  ckvT[idx] = ckv[(b * 2048 + t) * 640 + c];
}

// rowwise softmax over 2048, in-place on bf16 scores: p = softmax(s*scale + mask)
__global__ __launch_bounds__(256) void softmax_kernel(bf16* __restrict__ S,
                                                      const float* __restrict__ mask,
                                                      float scale)
{
  const int s = blockIdx.x;                          // 0..2047
  const int pair = blockIdx.y;                       // local pair in chunk
  bf16* row = S + ((long)pair * 2048 + s) * 2048;
  const float* mrow = mask + (long)s * 2048;         // mask pre-offset by b*S*S
  const int tid = threadIdx.x, lane = tid & 63, wave = tid >> 6;
  float v[8]; float mx = -3.4e38f;
  #pragma unroll
  for (int i = 0; i < 8; i++) {
    int t = tid + i * 256;
    v[i] = b2f(row[t]) * scale + mrow[t];
    mx = fmaxf(mx, v[i]);
  }
  #pragma unroll
  for (int off = 32; off; off >>= 1) mx = fmaxf(mx, __shfl_xor(mx, off));
  __shared__ float red[4];
  if (lane == 0) red[wave] = mx;
  __syncthreads();
  mx = fmaxf(fmaxf(red[0], red[1]), fmaxf(red[2], red[3]));
  float ss = 0.f;
  #pragma unroll
  for (int i = 0; i < 8; i++) { v[i] = __expf(v[i] - mx); ss += v[i]; }
  #pragma unroll
  for (int off = 32; off; off >>= 1) ss += __shfl_xor(ss, off);
  __syncthreads();                                   // red reuse
  if (lane == 0) red[wave] = ss;
  __syncthreads();
  ss = red[0] + red[1] + red[2] + red[3];
  float inv = 1.0f / ss;
  #pragma unroll
  for (int i = 0; i < 8; i++) {
    int t = tid + i * 256;
    row[t] = f2b(v[i] * inv);
  }
}

// ---------------------------------------------------------------------------

extern "C" void kernel_launch(void* const* d_in, const int* in_sizes, int n_in,
                              void* d_out, int out_size, void* d_ws, size_t ws_size,
                              hipStream_t stream)
{
  const float* hidden = (const float*)d_in[0];   // (2,2048,2048)
  const float* mask   = (const float*)d_in[1];   // (2,1,2048,2048)
  const float* qaW    = (const float*)d_in[2];   // (1536,2048)
  const float* qab    = (const float*)d_in[3];   // (1536,)
  const float* qanw   = (const float*)d_in[4];   // (1536,)
  const float* qbW    = (const float*)d_in[5];   // (4096,1536)
  const float* kvaW   = (const float*)d_in[6];   // (640,2048)
  const float* kvbW   = (const float*)d_in[7];   // (512,16,2,128)
  const float* oW     = (const float*)d_in[8];   // (2048,2048)
  float* out = (float*)d_out;                    // (2,2048,2048) f32
  (void)in_sizes; (void)n_in; (void)out_size;

  // ---- static workspace layout, total 144,179,200 B ----
  char* ws = (char*)d_ws;
  if (ws_size < 144179200u) return;   // diagnostic: absmax-fail (not crash) => ws too small

  // P0 [0, 83,886,080): Q640 (2,16,2048,640) bf16. Written from S6 (rope_q) onward.
  // Overlays inside P0 (ALL dead before S6):
  bf16* Q640    = (bf16*)(ws + 0);
  float* qa_f   = (float*)(ws + 0);           // (4096,1536) f32, S2-S3
  bf16* hiddenB = (bf16*)(ws + 25165824);     // 8,388,608 bf16, S1-S5
  bf16* qan     = (bf16*)(ws + 41943040);     // (4096,1536), S3-S4
  bf16* qaWB    = (bf16*)(ws + 54525952);     // (1536,2048), S1-S2
  bf16* qbWB    = (bf16*)(ws + 60817408);     // (4096,1536), S1-S4, ends 73,400,320
  // P1 [83,886,080, 117,440,512): time-shared qB (S4-S7) / Sbuf (S8) / attn_out (S9-S10)
  bf16* qB       = (bf16*)(ws + 83886080);    // (4096,4096) = (b,s,h,256)
  bf16* Sbuf     = (bf16*)(ws + 83886080);    // (4,2048,2048) score chunk
  bf16* attn_out = (bf16*)(ws + 83886080);    // (4096, 16*128)
  bf16* ckv     = (bf16*)(ws + 117440512);    // (2,2048,640)
  bf16* ckvT    = (bf16*)(ws + 122683392);    // (2,512,2048)
  bf16* kvaWB   = (bf16*)(ws + 126877696);    // (640,2048)
  bf16* kvbWB   = (bf16*)(ws + 129499136);    // (512,16,2,128)
  bf16* oWB     = (bf16*)(ws + 133693440);    // (2048,2048)
  bf16* oabsT   = (bf16*)(ws + 142082048);    // (16,128,512) -> end 144,179,200
  // outlat has NO buffer: PV writes into Q640 cols [0:512] (ldc=640) of consumed chunk.

  // ---- S1: converts ----
  cvt_kernel<<<dim3(32768), 256, 0, stream>>>(hidden, hiddenB, 8388608l);
  cvt_kernel<<<dim3(12288), 256, 0, stream>>>(qaW, qaWB, 3145728l);
  cvt_kernel<<<dim3(24576), 256, 0, stream>>>(qbW, qbWB, 6291456l);
  cvt_kernel<<<dim3(5120),  256, 0, stream>>>(kvaW, kvaWB, 1310720l);
  cvt_kernel<<<dim3(8192),  256, 0, stream>>>(kvbW, kvbWB, 2097152l);
  cvt_kernel<<<dim3(16384), 256, 0, stream>>>(oW, oWB, 4194304l);
  oabsT_kernel<<<dim3(4096), 256, 0, stream>>>(kvbW, oabsT);

  // ---- S2: q_a = hidden @ qaW^T (f32) ; S3: rmsnorm -> qan bf16 ----
  gemm_bt<false><<<dim3(32, 12, 1), 256, 0, stream>>>(hiddenB, qaWB, qa_f,
      4096, 1536, 2048, 2048, 2048, 1536, 0, 0, 0, 0, 0, 0, 1);
  rmsnorm_kernel<<<dim3(4096), 256, 0, stream>>>(qa_f, qab, qanw, qan);

  // ---- S4: q = qan @ qbW^T -> qB (b,s,h,256) bf16 ----
  gemm_bt<true><<<dim3(32, 32, 1), 256, 0, stream>>>(qan, qbWB, qB,
      4096, 4096, 1536, 1536, 1536, 4096, 0, 0, 0, 0, 0, 0, 1);

  // ---- S5: ckv_full = hidden @ kvaW^T -> (b,t,640) bf16 ----
  gemm_bt<true><<<dim3(32, 5, 1), 256, 0, stream>>>(hiddenB, kvaWB, ckv,
      4096, 640, 2048, 2048, 2048, 640, 0, 0, 0, 0, 0, 0, 1);

  // ---- S6: RoPE + transpose ----
  rope_k_kernel<<<dim3(1024), 256, 0, stream>>>(ckv);
  rope_q_kernel<<<dim3(16384), 256, 0, stream>>>(qB, Q640);
  ckvT_kernel<<<dim3(8192), 256, 0, stream>>>(ckv, ckvT);

  // ---- S7: q_lat = q_nope @ q_absorb^T -> Q640[...,0:512], z=(h,b) ----
  gemm_bt<true><<<dim3(16, 4, 32), 256, 0, stream>>>(qB, kvbWB, Q640,
      2048, 512, 128, 4096, 4096, 640,
      256l, 8388608l, 256l, 0l, 1310720l, 20971520l, 2);

  // ---- S8: scores GEMM -> softmax -> PV GEMM, chunks of 4 (b,h)-pairs ----
  const float scale = 1.0f / sqrtf(640.0f);
  for (int c = 0; c < 8; ++c) {
    int b = c / 4;
    bf16* Qchunk = Q640 + (long)c * 4 * 1310720;   // 4 pairs x (2048x640)
    gemm_bt<true><<<dim3(16, 16, 4), 256, 0, stream>>>(Qchunk, ckv + (long)b * 1310720, Sbuf,
        2048, 2048, 640, 640, 640, 2048,
        1310720l, 0l, 0l, 0l, 4194304l, 0l, 1);
    softmax_kernel<<<dim3(2048, 4), 256, 0, stream>>>(Sbuf, mask + (long)b * 4194304, scale);
    // PV: out_lat -> back into Q640 cols [0:512] of this (consumed) chunk, ldc=640
    gemm_bt<true><<<dim3(16, 4, 4), 256, 0, stream>>>(Sbuf, ckvT + (long)b * 1048576, Qchunk,
        2048, 512, 2048, 2048, 2048, 640,
        4194304l, 0l, 0l, 0l, 1310720l, 0l, 1);
  }

  // ---- S9: attn_out[b,s,h*128+d] = sum_c outlat[(b,h),s,c]*oabsT[h,d,c], z=(h,b) ----
  gemm_bt<true><<<dim3(16, 1, 32), 256, 0, stream>>>(Q640, oabsT, attn_out,
      2048, 128, 512, 640, 512, 2048,
      1310720l, 20971520l, 65536l, 0l, 128l, 4194304l, 2);

  // ---- S10: out = attn_out @ oW^T (f32, final) ----
  gemm_bt<false><<<dim3(32, 16, 1), 256, 0, stream>>>(attn_out, oWB, out,
      4096, 2048, 2048, 2048, 2048, 2048, 0, 0, 0, 0, 0, 0, 1);
}